// Round 6
// baseline (1352.557 us; speedup 1.0000x reference)
//
#include <hip/hip_runtime.h>

#define DIM 128
#define LDS_PAD 136   // shorts; 272 B row stride: 16B-aligned, 2-way bank alias (free)
#define BSHIFT 9
#define BROWS 512     // dst rows per bucket
#define SPLIT 4       // gather blocks per bucket (128 rows each)
#define QROWS 128     // rows per gather block
#define STG 16        // LDS staging slots per bucket (flush = 128B contiguous)
#define NB_MAX 448    // max buckets: 448*512 = 229K dst rows; LDS stage 57.3KB
#define CAPB 6144     // region capacity per bucket (mean 5120, sd ~72 -> +14 sigma)
#define ORDCAP 2048   // per-quarter edge cap (mean 1280, sd ~36 -> +21 sigma)
#define GA 192        // k_bin grid (few big blocks -> buckets fill, flushes coalesce)

typedef __attribute__((ext_vector_type(8))) short short8;
typedef __attribute__((ext_vector_type(4))) float f32x4;

static __device__ inline short f2bf(float f) {
    unsigned u = __builtin_bit_cast(unsigned, f);
    unsigned r = (u + 0x7FFF + ((u >> 16) & 1)) >> 16;  // RNE
    return (short)r;
}
static __device__ inline float bf2f(short s) {
    unsigned u = ((unsigned)(unsigned short)s) << 16;
    return __builtin_bit_cast(float, u);
}

// ---------------------------------------------------------------------------
// Weight transpose + f32->bf16: Wt[mat][n][k] = W[mat][k][n]
// ---------------------------------------------------------------------------
__global__ __launch_bounds__(256) void k_prep_w(const float* __restrict__ Wp,
                                                const float* __restrict__ Ws,
                                                short* __restrict__ Wt,
                                                int num_r) {
    int idx = blockIdx.x * 256 + threadIdx.x;
    int total = (1 + num_r) * DIM * DIM;
    if (idx >= total) return;
    int mat = idx >> 14;
    int rem = idx & 16383;
    int n = rem >> 7;
    int k = rem & 127;
    const float* src = (mat == 0) ? Wp : (Ws + (size_t)(mat - 1) * DIM * DIM);
    Wt[idx] = f2bf(src[(size_t)k * DIM + n]);
}

// ---------------------------------------------------------------------------
// Binning build (replaces the atomic slot build; R6):
// each edge contributes one entry per side: packed x = (dst&511)<<23 | src,
// y = valbits, appended to bucket dst>>9 (i-side buckets offset by NBu).
// LDS stage of STG entries per bucket; full buckets flush as ONE contiguous
// 128B write after a single global cursor bump. Global atomics: 2E/STG.
// Random 64B scatters: zero.
// ---------------------------------------------------------------------------
__global__ __launch_bounds__(256) void k_bin(const int* __restrict__ ro,
                                             const int* __restrict__ co,
                                             const float* __restrict__ va,
                                             int* __restrict__ gcur,
                                             int2* __restrict__ reg,
                                             int NBu, int NB, int E) {
    __shared__ int scnt[NB_MAX];
    __shared__ int2 sstage[NB_MAX * STG];
    int tid = threadIdx.x;
    for (int b = tid; b < NB; b += 256) scnt[b] = 0;
    __syncthreads();

    int per = (E + gridDim.x - 1) / gridDim.x;
    int e0 = blockIdx.x * per;
    int e1 = min(e0 + per, E);
    for (int base = e0; base < e1; base += 256) {
        int e = base + tid;
        bool valid = e < e1;
        int bu = 0, bi = 0;
        int2 pu = make_int2(0, 0), pi = make_int2(0, 0);
        if (valid) {
            int r_ = ro[e], c_ = co[e];
            int vb = __builtin_bit_cast(int, va[e]);
            bu = r_ >> BSHIFT;                 // u-side bucket
            pu = make_int2((int)((((unsigned)(r_ & (BROWS - 1))) << 23) | (unsigned)c_), vb);
            bi = NBu + (c_ >> BSHIFT);         // i-side bucket
            pi = make_int2((int)((((unsigned)(c_ & (BROWS - 1))) << 23) | (unsigned)r_), vb);
        }
        bool nu = valid, ni = valid;
        while (true) {
            if (nu) {
                int p = atomicAdd(&scnt[bu], 1);
                if (p < STG) { sstage[bu * STG + p] = pu; nu = false; }
            }
            if (ni) {
                int p = atomicAdd(&scnt[bi], 1);
                if (p < STG) { sstage[bi * STG + p] = pi; ni = false; }
            }
            int any = __syncthreads_or((int)(nu || ni));
            // flush full buckets: one thread per bucket, contiguous 128B write
            for (int b = tid; b < NB; b += 256) {
                if (scnt[b] >= STG) {
                    int g = atomicAdd(&gcur[b], STG);
                    if (g + STG <= CAPB) {
                        int2* dst = reg + (size_t)b * CAPB + g;
                        const int2* src = &sstage[b * STG];
#pragma unroll
                        for (int q = 0; q < STG; ++q) dst[q] = src[q];
                    }
                    scnt[b] = 0;
                }
            }
            __syncthreads();
            if (!any) break;
        }
    }
    // drain partial stages (entries < STG, still contiguous per bucket)
    for (int b = tid; b < NB; b += 256) {
        int c = scnt[b];
        if (c > STG) c = STG;
        if (c > 0) {
            int g = atomicAdd(&gcur[b], c);
            int2* dst = reg + (size_t)b * CAPB + g;
            for (int q = 0; q < c && g + q < CAPB; ++q) dst[q] = sstage[b * STG + q];
        }
    }
}

// ---------------------------------------------------------------------------
// GEMM body: C[M,128] = A[M,128] @ W (bf16 MFMA 16x16x32).
// A and C may alias (in-place row update): chunk fully staged to sA before
// any C write, chunks disjoint across blocks. Do NOT mark A/C __restrict__.
// ---------------------------------------------------------------------------
template <typename OUT>
__device__ __forceinline__ void gemm_body(const float* A, const short* __restrict__ Wt,
                                          OUT* C, int M, int bid, int nb,
                                          short* sA, short* sW) {
    int tid = threadIdx.x;
    int lane = tid & 63;
    int w = tid >> 6;
    int m = lane & 15;
    int q = lane >> 4;

    for (int j = tid; j < DIM * DIM / 8; j += 256) {
        int row = j >> 4;
        int c8 = (j & 15) * 8;
        int4 v = *(const int4*)&Wt[row * DIM + c8];
        *(int4*)&sW[row * LDS_PAD + c8] = v;
    }

    int nchunks = (M + DIM - 1) / DIM;
    for (int chunk = bid; chunk < nchunks; chunk += nb) {
        int row0 = chunk * DIM;
        __syncthreads();
        for (int j = tid; j < DIM * DIM / 4; j += 256) {
            int row = j >> 5;
            int c4 = (j & 31) * 4;
            int grow = row0 + row;
            if (grow >= M) grow = M - 1;
            float4 v = *(const float4*)&A[(size_t)grow * DIM + c4];
            short4 s = make_short4(f2bf(v.x), f2bf(v.y), f2bf(v.z), f2bf(v.w));
            *(short4*)&sA[row * LDS_PAD + c4] = s;
        }
        __syncthreads();

        f32x4 acc[2][8];
#pragma unroll
        for (int i = 0; i < 2; ++i)
#pragma unroll
            for (int j = 0; j < 8; ++j) acc[i][j] = (f32x4){0.f, 0.f, 0.f, 0.f};

#pragma unroll
        for (int kt = 0; kt < 4; ++kt) {
            int k0 = kt * 32 + q * 8;
            short8 a0 = *(const short8*)&sA[(w * 32 + m) * LDS_PAD + k0];
            short8 a1 = *(const short8*)&sA[(w * 32 + 16 + m) * LDS_PAD + k0];
#pragma unroll
            for (int j = 0; j < 8; ++j) {
                short8 b = *(const short8*)&sW[(j * 16 + m) * LDS_PAD + k0];
                acc[0][j] = __builtin_amdgcn_mfma_f32_16x16x32_bf16(a0, b, acc[0][j], 0, 0, 0);
                acc[1][j] = __builtin_amdgcn_mfma_f32_16x16x32_bf16(a1, b, acc[1][j], 0, 0, 0);
            }
        }

#pragma unroll
        for (int i = 0; i < 2; ++i) {
#pragma unroll
            for (int r = 0; r < 4; ++r) {
                int row = row0 + w * 32 + i * 16 + q * 4 + r;
                if (row < M) {
#pragma unroll
                    for (int j = 0; j < 8; ++j) {
                        float v = acc[i][j][r];
                        if constexpr (sizeof(OUT) == 2)
                            C[(size_t)row * DIM + j * 16 + m] = f2bf(v);
                        else
                            C[(size_t)row * DIM + j * 16 + m] = v;
                    }
                }
            }
        }
    }
}

__global__ __launch_bounds__(256) void k_gemm_pair(const float* A0, const short* W0,
                                                   short* C0, int M0,
                                                   const float* A1, const short* W1,
                                                   float* C1, int M1, int half) {
    __shared__ short sA[DIM * LDS_PAD];
    __shared__ short sW[DIM * LDS_PAD];
    if (blockIdx.x < half)
        gemm_body<short>(A0, W0, C0, M0, blockIdx.x, half, sA, sW);
    else
        gemm_body<float>(A1, W1, C1, M1, blockIdx.x - half, gridDim.x - half, sA, sW);
}

// ---------------------------------------------------------------------------
// Gather (R6): per bucket-quarter block, build a micro-CSR in LDS
// (count -> wave prefix scan -> ushort index scatter), then the proven
// 16-lane-per-row T-accumulate. Bucket edges stay hot in L2 across the
// three scans. Tail blocks past the gather range: fused leaky-ReLU.
// ---------------------------------------------------------------------------
__global__ __launch_bounds__(256) void k_gather(const int* __restrict__ gcur,
                                                const int2* __restrict__ reg,
                                                const short* __restrict__ T,
                                                float* out, int n, int bucket_base,
                                                int relu, float* relu_x, long relu_n4) {
    int bb = blockIdx.x;
    int nbb = ((n + BROWS - 1) >> BSHIFT) * SPLIT;
    int tid = threadIdx.x;
    if (bb >= nbb) {
        long i = (long)(bb - nbb) * 256 + tid;
        if (i < relu_n4) {
            float4 v = ((float4*)relu_x)[i];
            v.x = v.x > 0.f ? v.x : 0.01f * v.x;
            v.y = v.y > 0.f ? v.y : 0.01f * v.y;
            v.z = v.z > 0.f ? v.z : 0.01f * v.z;
            v.w = v.w > 0.f ? v.w : 0.01f * v.w;
            ((float4*)relu_x)[i] = v;
        }
        return;
    }
    int bl = bb >> 2, quarter = bb & 3;
    int bucket = bucket_base + bl;
    int row0 = (bl << BSHIFT) + quarter * QROWS;
    int cnt = gcur[bucket];
    if (cnt > CAPB) cnt = CAPB;
    const int2* eg = reg + (size_t)bucket * CAPB;

    __shared__ int cnt2[QROWS];
    __shared__ int off2[QROWS + 1];
    __shared__ int cur2[QROWS];
    __shared__ int wtot[2];
    __shared__ unsigned short ord[ORDCAP];

    if (tid < QROWS) cnt2[tid] = 0;
    __syncthreads();
    // pass 1: count per local row (this quarter only)
    for (int k = tid; k < cnt; k += 256) {
        unsigned w = (unsigned)eg[k].x;
        int dl = (int)(w >> 23);
        if ((dl >> 7) == quarter) atomicAdd(&cnt2[dl & (QROWS - 1)], 1);
    }
    __syncthreads();
    // exclusive prefix scan of 128 counts (2 waves + cross-wave base)
    int orig = (tid < QROWS) ? cnt2[tid] : 0;
    int v = orig;
    int lane = tid & 63;
#pragma unroll
    for (int d = 1; d < 64; d <<= 1) {
        int t = __shfl_up(v, d);
        if (lane >= d) v += t;
    }
    if (lane == 63 && tid < QROWS) wtot[tid >> 6] = v;
    __syncthreads();
    if (tid < QROWS) {
        int bsum = (tid >= 64) ? wtot[0] : 0;
        int ex = bsum + v - orig;
        off2[tid] = ex;
        cur2[tid] = ex;
        if (tid == QROWS - 1) off2[QROWS] = bsum + v;
    }
    __syncthreads();
    // pass 2: scatter edge indices into CSR order
    for (int k = tid; k < cnt; k += 256) {
        unsigned w = (unsigned)eg[k].x;
        int dl = (int)(w >> 23);
        if ((dl >> 7) == quarter) {
            int p = atomicAdd(&cur2[dl & (QROWS - 1)], 1);
            if (p < ORDCAP) ord[p] = (unsigned short)k;
        }
    }
    __syncthreads();
    // pass 3: per-row gather (16-lane groups, 4-edge unroll)
    int g = tid >> 4, l = tid & 15;
    for (int lr = g; lr < QROWS; lr += 16) {
        int row = row0 + lr;
        if (row >= n) continue;
        int s = off2[lr], e2 = off2[lr + 1];
        if (s > ORDCAP) s = ORDCAP;
        if (e2 > ORDCAP) e2 = ORDCAP;
        float acc[8];
#pragma unroll
        for (int i = 0; i < 8; ++i) acc[i] = 0.f;
        float vsum = 0.f;
        int j = s;
        for (; j + 4 <= e2; j += 4) {
            int k0 = ord[j], k1 = ord[j + 1], k2 = ord[j + 2], k3 = ord[j + 3];
            int2 E0 = eg[k0], E1 = eg[k1], E2 = eg[k2], E3 = eg[k3];
            short8 t0 = *(const short8*)&T[(size_t)(E0.x & 0x7FFFFF) * DIM + l * 8];
            short8 t1 = *(const short8*)&T[(size_t)(E1.x & 0x7FFFFF) * DIM + l * 8];
            short8 t2 = *(const short8*)&T[(size_t)(E2.x & 0x7FFFFF) * DIM + l * 8];
            short8 t3 = *(const short8*)&T[(size_t)(E3.x & 0x7FFFFF) * DIM + l * 8];
            float f0 = __builtin_bit_cast(float, E0.y);
            float f1 = __builtin_bit_cast(float, E1.y);
            float f2 = __builtin_bit_cast(float, E2.y);
            float f3 = __builtin_bit_cast(float, E3.y);
            vsum += (f0 + f1) + (f2 + f3);
#pragma unroll
            for (int i = 0; i < 8; ++i) {
                acc[i] += f0 * bf2f(t0[i]);
                acc[i] += f1 * bf2f(t1[i]);
                acc[i] += f2 * bf2f(t2[i]);
                acc[i] += f3 * bf2f(t3[i]);
            }
        }
        for (; j < e2; ++j) {
            int k0 = ord[j];
            int2 E0 = eg[k0];
            short8 t0 = *(const short8*)&T[(size_t)(E0.x & 0x7FFFFF) * DIM + l * 8];
            float f0 = __builtin_bit_cast(float, E0.y);
            vsum += f0;
#pragma unroll
            for (int i = 0; i < 8; ++i) acc[i] += f0 * bf2f(t0[i]);
        }
        float dv = 1.0f / (vsum + 1.0f);
        float4* op = (float4*)&out[(size_t)row * DIM + l * 8];
        float4 o0 = op[0], o1 = op[1];
        o0.x += dv * acc[0]; o0.y += dv * acc[1]; o0.z += dv * acc[2]; o0.w += dv * acc[3];
        o1.x += dv * acc[4]; o1.y += dv * acc[5]; o1.z += dv * acc[6]; o1.w += dv * acc[7];
        if (relu) {
            o0.x = o0.x > 0.f ? o0.x : 0.01f * o0.x;
            o0.y = o0.y > 0.f ? o0.y : 0.01f * o0.y;
            o0.z = o0.z > 0.f ? o0.z : 0.01f * o0.z;
            o0.w = o0.w > 0.f ? o0.w : 0.01f * o0.w;
            o1.x = o1.x > 0.f ? o1.x : 0.01f * o1.x;
            o1.y = o1.y > 0.f ? o1.y : 0.01f * o1.y;
            o1.z = o1.z > 0.f ? o1.z : 0.01f * o1.z;
            o1.w = o1.w > 0.f ? o1.w : 0.01f * o1.w;
        }
        op[0] = o0;
        op[1] = o1;
    }
}

// ---------------------------------------------------------------------------
static inline size_t align4(size_t x) { return (x + 3) & ~(size_t)3; }

extern "C" void kernel_launch(void* const* d_in, const int* in_sizes, int n_in,
                              void* d_out, int out_size, void* d_ws, size_t ws_size,
                              hipStream_t stream) {
    const float* u_in = (const float*)d_in[0];
    const float* i_in = (const float*)d_in[1];
    const float* Wp   = (const float*)d_in[2];
    const float* Ws   = (const float*)d_in[3];
    const float* vals = (const float*)d_in[4];
    const int*   rows = (const int*)d_in[5];
    const int*   cols = (const int*)d_in[6];

    int n_u   = in_sizes[0] / DIM;
    int n_i   = in_sizes[1] / DIM;
    int num_r = in_sizes[3] / (DIM * DIM);
    int E     = in_sizes[4] / num_r;

    int NBu = (n_u + BROWS - 1) >> BSHIFT;
    int NBi = (n_i + BROWS - 1) >> BSHIFT;
    int NB  = NBu + NBi;   // must be <= NB_MAX (392 for 100K+100K)

    size_t matu = (size_t)n_u * DIM;
    size_t tsz  = ((n_u > n_i ? n_u : n_i)) * (size_t)DIM;

    // ---- workspace layout (4-byte words) ----
    float* ws = (float*)d_ws;
    size_t o = 0;
    short* T    = (short*)(ws + o); o += align4(tsz / 2 + 2);
    short* Wt   = (short*)(ws + o); o += align4((size_t)(1 + num_r) * DIM * DIM / 2);
    int*  gcur  = (int*)(ws + o);   o += align4(NB);
    int2* reg   = (int2*)(ws + o);  o += (size_t)NB * CAPB * 2;

    float* out_u = (float*)d_out;
    float* out_i = out_u + matu;

    // ---- weight transpose+convert (once) ----
    int wtot = (1 + num_r) * DIM * DIM;
    k_prep_w<<<(wtot + 255) / 256, 256, 0, stream>>>(Wp, Ws, Wt, num_r);
    const short* Wt_p = Wt;

    const float* u_cur = u_in;
    const float* i_cur = i_in;
    const int GHALF = 512;
    long n4u = (long)matu / 4;

    // build(0)
    hipMemsetAsync(gcur, 0, (size_t)NB * sizeof(int), stream);
    k_bin<<<GA, 256, 0, stream>>>(rows, cols, vals, gcur, reg, NBu, NB, E);

    for (int r = 0; r < num_r; ++r) {
        int last = (r == num_r - 1);
        const short* Wt_r = Wt + (size_t)(1 + r) * DIM * DIM;

        // ---- u phase: out_u = u_cur@Wp + div_u * gather(T = i_cur@Wr) ----
        k_gemm_pair<<<2 * GHALF, 256, 0, stream>>>(i_cur, Wt_r, T, n_i,
                                                   u_cur, Wt_p, out_u, n_u, GHALF);
        k_gather<<<NBu * SPLIT, 256, 0, stream>>>(gcur, reg, T, out_u, n_u, 0, 0,
                                                  (float*)0, 0);
        u_cur = out_u;

        // ---- i phase (fused leaky-ReLU on last round; relu_u rides as tail) ----
        k_gemm_pair<<<2 * GHALF, 256, 0, stream>>>(u_cur, Wt_r, T, n_u,
                                                   i_cur, Wt_p, out_i, n_i, GHALF);
        {
            long rn4 = last ? n4u : 0;
            int grelu = last ? (int)((rn4 + 255) / 256) : 0;
            k_gather<<<NBi * SPLIT + grelu, 256, 0, stream>>>(gcur, reg, T, out_i, n_i,
                                                              NBu, last, out_u, rn4);
        }
        i_cur = out_i;

        // ---- build(r+1): regions single-buffered, safe after gather_i(r) ----
        if (!last) {
            hipMemsetAsync(gcur, 0, (size_t)NB * sizeof(int), stream);
            k_bin<<<GA, 256, 0, stream>>>(rows + (size_t)(r + 1) * E,
                                          cols + (size_t)(r + 1) * E,
                                          vals + (size_t)(r + 1) * E,
                                          gcur, reg, NBu, NB, E);
        }
    }
}